// Round 1
// 460.723 us; speedup vs baseline: 1.0923x; 1.0923x over previous
//
#include <hip/hip_runtime.h>
#include <math.h>
#include <float.h>

#define Hh 512
#define Ww 512
#define HWW (Hh*Ww)
#define NP 262144
#define KMAX 16
#define PPB 32   // points per block (8 threads per point, 256-thread blocks)

// Record per point: 8 floats = 32B: {depth, next(bits), alpha, r | g, b, -, -}
// Walk needs only the leading float2 {depth, next}.
// Ordering key = (depth_bits << 32) | point_idx  (depth > 0.2 -> bits monotonic),
// matching lexsort((depth, pid)) with stable tie-break by original index.

__device__ __forceinline__ unsigned long long umin64(unsigned long long a,
                                                     unsigned long long b){
    return a < b ? a : b;
}

__global__ __launch_bounds__(256) void point_kernel(
    const float* __restrict__ positions,
    const float* __restrict__ trivecs,
    const float* __restrict__ densities,
    const float* __restrict__ shs,
    const float* __restrict__ viewm,
    const float* __restrict__ projm,
    const float* __restrict__ campos,
    const float* __restrict__ aabb,
    float* __restrict__ recs,
    int* __restrict__ heads)
{
#pragma clang fp contract(off)
    // 32 points * 216 floats = 1728 float4 = 27648 B, float4-aligned
    __shared__ float4 sh4[PPB*54];

    const int tid = threadIdx.x;
    const int n0  = blockIdx.x * PPB;
    const int p   = tid >> 3;   // local point 0..31
    const int r   = tid & 7;    // rank 0..7
    const int n   = n0 + p;

    // ---------- coalesced staging loads: lane i reads base + i*16B ----------
    const float4* gsh = (const float4*)(shs + (size_t)n0*216);
    float4 sb0 = gsh[tid];
    float4 sb1 = gsh[tid +  256];
    float4 sb2 = gsh[tid +  512];
    float4 sb3 = gsh[tid +  768];
    float4 sb4 = gsh[tid + 1024];
    float4 sb5 = gsh[tid + 1280];
    float4 sb6;
    const int  i6   = tid + 1536;
    const bool has6 = (i6 < 1728);            // 1728 = 6.75 * 256
    if (has6) sb6 = gsh[i6];

    // perfectly coalesced: (n0+p)*8 + r == n0*8 + tid
    float den = densities[(size_t)n0*8 + tid];

    // this lane's rank row mid-column (D/2=4): 3 scattered scalars (compulsory lines)
    const float* tv = trivecs + (size_t)n*192 + r*24;
    float m0 = tv[4], m1 = tv[12], m2 = tv[20];

    float px = positions[n*3+0], py = positions[n*3+1], pz = positions[n*3+2];

    // ---------- LDS stage ----------
    sh4[tid]        = sb0;
    sh4[tid +  256] = sb1;
    sh4[tid +  512] = sb2;
    sh4[tid +  768] = sb3;
    sh4[tid + 1024] = sb4;
    sh4[tid + 1280] = sb5;
    if (has6) sh4[i6] = sb6;

    // ---------- geometry (bit-identical to baseline; redundant per 8-lane group) ----------
    float wx = aabb[0] + px*aabb[3];
    float wy = aabb[1] + py*aabb[4];
    float wz = aabb[2] + pz*aabb[5];

    float phx = ((wx*projm[0] + wy*projm[4]) + wz*projm[8])  + projm[12];
    float phy = ((wx*projm[1] + wy*projm[5]) + wz*projm[9])  + projm[13];
    float phw = ((wx*projm[3] + wy*projm[7]) + wz*projm[11]) + projm[15];
    float denom = phw + 1e-7f;
    float ndcx = phx / denom;
    float ndcy = phy / denom;
    float depth = ((wx*viewm[2] + wy*viewm[6]) + wz*viewm[10]) + viewm[14];

    float fx = ((ndcx + 1.0f)*(float)Ww - 1.0f)*0.5f;
    float fy = ((ndcy + 1.0f)*(float)Hh - 1.0f)*0.5f;
    int ix = (int)rintf(fx);
    int iy = (int)rintf(fy);
    bool valid = (depth > 0.2f) && (ix >= 0) && (ix < Ww) && (iy >= 0) && (iy < Hh);
    int pid = valid ? (iy*Ww + ix) : -1;

    // ---------- density / alpha: one rank per lane, 8-lane xor-reduce ----------
    float tri = m0*m1*m2;
    tri = tri > 0.0f ? tri : 0.0f;
    float s = expf(den - 2.0f) * tri;
    float sig = s;
    sig += __shfl_xor(sig, 1, 64);
    sig += __shfl_xor(sig, 2, 64);
    sig += __shfl_xor(sig, 4, 64);
    float alpha = 1.0f - expf(-sig);
    alpha = fminf(alpha, 0.999f);
    alpha = fmaxf(alpha, 0.0f);

    // ---------- SH basis ----------
    float dxr = wx - campos[0], dyr = wy - campos[1], dzr = wz - campos[2];
    float nrm = sqrtf((dxr*dxr + dyr*dyr) + dzr*dzr) + 1e-8f;
    float x = dxr/nrm, y = dyr/nrm, z = dzr/nrm;
    float basis[9];
    basis[0] = 0.28209479177387814f;
    basis[1] = -0.4886025119029199f * y;
    basis[2] =  0.4886025119029199f * z;
    basis[3] = -0.4886025119029199f * x;
    basis[4] =  1.0925484305920792f * (x*y);
    basis[5] = -1.0925484305920792f * (y*z);
    basis[6] =  0.31539156525252005f * (2.0f*z*z - x*x - y*y);
    basis[7] = -1.0925484305920792f * (x*z);
    basis[8] =  0.5462742152960396f * (x*x - y*y);

    __syncthreads();

    // this lane's rank SH block: 27 consecutive floats in LDS
    // bank check: addr/4 mod 32 = (24p + 27r + K) mod 32 covers all 32 banks
    // exactly twice across 64 lanes -> 2-way (free, m136)
    const float* shr = (const float*)sh4 + p*216 + r*27;
    float d0 = 0.f, d1 = 0.f, d2 = 0.f;
    #pragma unroll
    for (int k = 0; k < 9; k++){
        float b = basis[k];
        d0 = fmaf(b, shr[3*k+0], d0);
        d1 = fmaf(b, shr[3*k+1], d1);
        d2 = fmaf(b, shr[3*k+2], d2);
    }
    float invs = 1.0f/(sig + 1e-8f);
    float wr = s*invs;
    float cr = wr*fmaxf(d0 + 0.5f, 0.0f);
    float cg = wr*fmaxf(d1 + 0.5f, 0.0f);
    float cb = wr*fmaxf(d2 + 0.5f, 0.0f);
    cr += __shfl_xor(cr, 1, 64); cr += __shfl_xor(cr, 2, 64); cr += __shfl_xor(cr, 4, 64);
    cg += __shfl_xor(cg, 1, 64); cg += __shfl_xor(cg, 2, 64); cg += __shfl_xor(cg, 4, 64);
    cb += __shfl_xor(cb, 1, 64); cb += __shfl_xor(cb, 2, 64); cb += __shfl_xor(cb, 4, 64);

    if (r == 0 && pid >= 0){
        int next = atomicExch(&heads[pid], n);
        float4* rp = (float4*)(recs + (size_t)n*8);
        rp[0] = make_float4(depth, __int_as_float(next), alpha, cr);
        *(float2*)(recs + (size_t)n*8 + 4) = make_float2(cg, cb);
    }
}

__global__ __launch_bounds__(256) void composite_kernel(
    const int* __restrict__ heads,
    const float* __restrict__ recs,
    const float* __restrict__ bg,
    float* __restrict__ out)
{
    int p = blockIdx.x * blockDim.x + threadIdx.x;
    if (p >= HWW) return;

    const unsigned long long NONE = ~0ull;
    unsigned long long keys[KMAX];
    int cur = heads[p];

    // scratch-free walk: fully unrolled, compile-time indices only
    #pragma unroll
    for (int i = 0; i < KMAX; i++){
        unsigned long long k = NONE;
        if (cur >= 0){
            float2 dn = *(const float2*)(recs + (size_t)cur*8);
            k = ((unsigned long long)__float_as_uint(dn.x) << 32) |
                (unsigned int)cur;
            cur = __float_as_int(dn.y);
        }
        keys[i] = k;
    }
    bool overflow = (cur >= 0);

    float T = 1.0f, accA = 0.f, accD = 0.f, aR = 0.f, aG = 0.f, aB = 0.f;

    if (!overflow){
        for (int it = 0; it < KMAX; ++it){
            // tree min over keys[] — all compile-time indices
            unsigned long long m0 = umin64(keys[0],  keys[1]);
            unsigned long long m1 = umin64(keys[2],  keys[3]);
            unsigned long long m2 = umin64(keys[4],  keys[5]);
            unsigned long long m3 = umin64(keys[6],  keys[7]);
            unsigned long long m4 = umin64(keys[8],  keys[9]);
            unsigned long long m5 = umin64(keys[10], keys[11]);
            unsigned long long m6 = umin64(keys[12], keys[13]);
            unsigned long long m7 = umin64(keys[14], keys[15]);
            m0 = umin64(m0, m1); m2 = umin64(m2, m3);
            m4 = umin64(m4, m5); m6 = umin64(m6, m7);
            m0 = umin64(m0, m2); m4 = umin64(m4, m6);
            unsigned long long m = umin64(m0, m4);

            if (!__any(m != NONE)) break;   // wave-uniform early exit

            if (m != NONE){
                int nidx = (int)(m & 0xffffffffu);
                float4 ra = *(const float4*)(recs + (size_t)nidx*8);
                float2 rb = *(const float2*)(recs + (size_t)nidx*8 + 4);
                float a = ra.z, w = a*T;
                aR += w*ra.w; aG += w*rb.x; aB += w*rb.y;
                accA += w; accD += w*ra.x;
                T *= (1.0f - a);
                #pragma unroll
                for (int j = 0; j < KMAX; j++)
                    keys[j] = (keys[j] == m) ? NONE : keys[j];
            }
        }
    } else {
        // statistically-unreachable overflow: exact selection over the list
        unsigned long long last = 0; bool haveLast = false;
        for (;;){
            unsigned long long best = NONE;
            for (int c2 = heads[p]; c2 >= 0; ){
                float2 dn = *(const float2*)(recs + (size_t)c2*8);
                unsigned long long k =
                    ((unsigned long long)__float_as_uint(dn.x) << 32) |
                    (unsigned int)c2;
                if ((!haveLast || k > last) && k < best) best = k;
                c2 = __float_as_int(dn.y);
            }
            if (best == NONE) break;
            int nidx = (int)(best & 0xffffffffu);
            float4 ra = *(const float4*)(recs + (size_t)nidx*8);
            float2 rb = *(const float2*)(recs + (size_t)nidx*8 + 4);
            float a = ra.z, w = a*T;
            aR += w*ra.w; aG += w*rb.x; aB += w*rb.y;
            accA += w; accD += w*ra.x;
            T *= (1.0f - a);
            last = best; haveLast = true;
        }
    }

    float om = 1.0f - accA;
    out[p]         = aR + om*bg[0];
    out[HWW + p]   = aG + om*bg[1];
    out[2*HWW + p] = aB + om*bg[2];
    out[3*HWW + p] = accD;
    out[4*HWW + p] = accA;
    out[5*HWW + p] = accD/(accA + 1e-8f);
}

extern "C" void kernel_launch(void* const* d_in, const int* in_sizes, int n_in,
                              void* d_out, int out_size, void* d_ws, size_t ws_size,
                              hipStream_t stream)
{
    const float* positions = (const float*)d_in[0];
    const float* trivecs   = (const float*)d_in[1];
    const float* densities = (const float*)d_in[2];
    const float* shs       = (const float*)d_in[3];
    const float* viewm     = (const float*)d_in[4];
    const float* projm     = (const float*)d_in[5];
    const float* campos    = (const float*)d_in[6];
    const float* aabb      = (const float*)d_in[7];
    const float* bg        = (const float*)d_in[8];
    float* out = (float*)d_out;

    char* ws = (char*)d_ws;
    size_t o = 0;
    int*   heads = (int*)(ws + o);   o += (size_t)HWW*4;
    float* recs  = (float*)(ws + o); o += (size_t)NP*32;

    hipMemsetAsync(heads, 0xFF, (size_t)HWW*4, stream);   // all -1
    point_kernel<<<NP/PPB, 256, 0, stream>>>(positions, trivecs, densities, shs,
                                             viewm, projm, campos, aabb,
                                             recs, heads);
    composite_kernel<<<HWW/256, 256, 0, stream>>>(heads, recs, bg, out);
}

// Round 2
// 460.116 us; speedup vs baseline: 1.0937x; 1.0013x over previous
//
#include <hip/hip_runtime.h>
#include <math.h>
#include <float.h>

#define Hh 512
#define Ww 512
#define HWW (Hh*Ww)
#define NP 262144
#define KMAX 16
#define PPB 32   // points per block (8 threads per point, 256-thread blocks)

#if defined(__has_builtin)
#if __has_builtin(__builtin_amdgcn_global_load_lds)
#define HAVE_GLL 1
#endif
#endif

typedef const __attribute__((address_space(1))) void cg_void;
typedef __attribute__((address_space(3))) void s_void;

// Record per point: 8 floats = 32B: {depth, next(bits), alpha, r | g, b, -, -}
// Ordering key = (depth_bits << 32) | point_idx, matching lexsort((depth, pid)).

__device__ __forceinline__ unsigned long long umin64(unsigned long long a,
                                                     unsigned long long b){
    return a < b ? a : b;
}

__global__ __launch_bounds__(256) void point_kernel(
    const float* __restrict__ positions,
    const float* __restrict__ trivecs,
    const float* __restrict__ densities,
    const float* __restrict__ shs,
    const float* __restrict__ viewm,
    const float* __restrict__ projm,
    const float* __restrict__ campos,
    const float* __restrict__ aabb,
    float* __restrict__ recs,
    int* __restrict__ heads)
{
#pragma clang fp contract(off)
    // 32 points * 216 floats = 1728 float4 = 27648 B
    __shared__ float4 sh4[PPB*54];
    // 32 points * 24 mid floats = 3072 B; mid[f], f = p*24 + 3r + c
    __shared__ float  mid_lds[PPB*24];

    const int tid = threadIdx.x;
    const int n0  = blockIdx.x * PPB;
    const int p   = tid >> 3;   // local point 0..31
    const int r   = tid & 7;    // rank 0..7
    const int n   = n0 + p;

    // ---------- shs staging: async global->LDS, linear lane order ----------
    const float4* gsh = (const float4*)(shs + (size_t)n0*216);
    const int wb = tid & ~63;   // wave-uniform LDS base offset
#ifdef HAVE_GLL
    #pragma unroll
    for (int j = 0; j < 6; j++)
        __builtin_amdgcn_global_load_lds((cg_void*)(gsh + j*256 + tid),
                                         (s_void*)(sh4 + j*256 + wb), 16, 0, 0);
    if (tid < 192)   // wave-uniform: waves 0..2 (1728 = 6*256 + 192)
        __builtin_amdgcn_global_load_lds((cg_void*)(gsh + 1536 + tid),
                                         (s_void*)(sh4 + 1536 + wb), 16, 0, 0);
#else
    {
        float4 sb0 = gsh[tid],       sb1 = gsh[tid +  256], sb2 = gsh[tid + 512];
        float4 sb3 = gsh[tid + 768], sb4 = gsh[tid + 1024], sb5 = gsh[tid + 1280];
        float4 sb6; const bool h6 = (tid + 1536 < 1728);
        if (h6) sb6 = gsh[tid + 1536];
        sh4[tid] = sb0; sh4[tid+256] = sb1; sh4[tid+512] = sb2;
        sh4[tid+768] = sb3; sh4[tid+1024] = sb4; sh4[tid+1280] = sb5;
        if (h6) sh4[tid+1536] = sb6;
    }
#endif

    // ---------- trivec mids: odd-float4 coalesced loads (32B stride) ----------
    // mid for (point pL, rank r, col c) is float4 index pL*48 + 6r+2c+1, .x
    // flat f = pL*24 + (3r+c); odd index o = 2*(f%24)+1
    const float4* gtv = (const float4*)trivecs;   // N*48 float4
    float4 t0, t1, t2;
    {
        const int f0 = tid, f1 = tid + 256, f2 = tid + 512;
        t0 = gtv[(size_t)(n0 + f0/24)*48 + (size_t)((f0%24)*2 + 1)];
        t1 = gtv[(size_t)(n0 + f1/24)*48 + (size_t)((f1%24)*2 + 1)];
        t2 = gtv[(size_t)(n0 + f2/24)*48 + (size_t)((f2%24)*2 + 1)];
    }

    // perfectly coalesced: (n0+p)*8 + r == n0*8 + tid
    float den = densities[(size_t)n0*8 + tid];

    float px = positions[n*3+0], py = positions[n*3+1], pz = positions[n*3+2];

    // mid LDS writes: stride-1 in lane order (2-way, free)
    mid_lds[tid]       = t0.x;
    mid_lds[tid + 256] = t1.x;
    mid_lds[tid + 512] = t2.x;

    // ---------- geometry (overlaps in-flight shs loads; bit-identical) ----------
    float wx = aabb[0] + px*aabb[3];
    float wy = aabb[1] + py*aabb[4];
    float wz = aabb[2] + pz*aabb[5];

    float phx = ((wx*projm[0] + wy*projm[4]) + wz*projm[8])  + projm[12];
    float phy = ((wx*projm[1] + wy*projm[5]) + wz*projm[9])  + projm[13];
    float phw = ((wx*projm[3] + wy*projm[7]) + wz*projm[11]) + projm[15];
    float denom = phw + 1e-7f;
    float ndcx = phx / denom;
    float ndcy = phy / denom;
    float depth = ((wx*viewm[2] + wy*viewm[6]) + wz*viewm[10]) + viewm[14];

    float fx = ((ndcx + 1.0f)*(float)Ww - 1.0f)*0.5f;
    float fy = ((ndcy + 1.0f)*(float)Hh - 1.0f)*0.5f;
    int ix = (int)rintf(fx);
    int iy = (int)rintf(fy);
    bool valid = (depth > 0.2f) && (ix >= 0) && (ix < Ww) && (iy >= 0) && (iy < Hh);
    int pid = valid ? (iy*Ww + ix) : -1;

    // ---------- SH basis (independent of LDS) ----------
    float dxr = wx - campos[0], dyr = wy - campos[1], dzr = wz - campos[2];
    float nrm = sqrtf((dxr*dxr + dyr*dyr) + dzr*dzr) + 1e-8f;
    float x = dxr/nrm, y = dyr/nrm, z = dzr/nrm;
    float basis[9];
    basis[0] = 0.28209479177387814f;
    basis[1] = -0.4886025119029199f * y;
    basis[2] =  0.4886025119029199f * z;
    basis[3] = -0.4886025119029199f * x;
    basis[4] =  1.0925484305920792f * (x*y);
    basis[5] = -1.0925484305920792f * (y*z);
    basis[6] =  0.31539156525252005f * (2.0f*z*z - x*x - y*y);
    basis[7] = -1.0925484305920792f * (x*z);
    basis[8] =  0.5462742152960396f * (x*x - y*y);

    __syncthreads();   // drains vmcnt (incl. global_load_lds) + lgkm

    // ---------- density / alpha: one rank per lane, 8-lane xor-reduce ----------
    // reader index: p*24 + 3r + c = 3*lane + c  (2-way across 64 lanes, free)
    const float* mp = mid_lds + (p*24 + r*3);
    float m0 = mp[0], m1 = mp[1], m2 = mp[2];
    float tri = m0*m1*m2;
    tri = tri > 0.0f ? tri : 0.0f;
    float s = expf(den - 2.0f) * tri;
    float sig = s;
    sig += __shfl_xor(sig, 1, 64);
    sig += __shfl_xor(sig, 2, 64);
    sig += __shfl_xor(sig, 4, 64);
    float alpha = 1.0f - expf(-sig);
    alpha = fminf(alpha, 0.999f);
    alpha = fmaxf(alpha, 0.0f);

    // ---------- SH color from LDS ----------
    const float* shr = (const float*)sh4 + p*216 + r*27;
    float d0 = 0.f, d1 = 0.f, d2 = 0.f;
    #pragma unroll
    for (int k = 0; k < 9; k++){
        float b = basis[k];
        d0 = fmaf(b, shr[3*k+0], d0);
        d1 = fmaf(b, shr[3*k+1], d1);
        d2 = fmaf(b, shr[3*k+2], d2);
    }
    float invs = 1.0f/(sig + 1e-8f);
    float wr = s*invs;
    float cr = wr*fmaxf(d0 + 0.5f, 0.0f);
    float cg = wr*fmaxf(d1 + 0.5f, 0.0f);
    float cb = wr*fmaxf(d2 + 0.5f, 0.0f);
    cr += __shfl_xor(cr, 1, 64); cr += __shfl_xor(cr, 2, 64); cr += __shfl_xor(cr, 4, 64);
    cg += __shfl_xor(cg, 1, 64); cg += __shfl_xor(cg, 2, 64); cg += __shfl_xor(cg, 4, 64);
    cb += __shfl_xor(cb, 1, 64); cb += __shfl_xor(cb, 2, 64); cb += __shfl_xor(cb, 4, 64);

    if (r == 0 && pid >= 0){
        int next = atomicExch(&heads[pid], n);
        float4* rp = (float4*)(recs + (size_t)n*8);
        rp[0] = make_float4(depth, __int_as_float(next), alpha, cr);
        *(float2*)(recs + (size_t)n*8 + 4) = make_float2(cg, cb);
    }
}

__global__ __launch_bounds__(256) void composite_kernel(
    const int* __restrict__ heads,
    const float* __restrict__ recs,
    const float* __restrict__ bg,
    float* __restrict__ out)
{
    int p = blockIdx.x * blockDim.x + threadIdx.x;
    if (p >= HWW) return;

    const unsigned long long NONE = ~0ull;
    unsigned long long keys[KMAX];
    int cur = heads[p];

    #pragma unroll
    for (int i = 0; i < KMAX; i++){
        unsigned long long k = NONE;
        if (cur >= 0){
            float2 dn = *(const float2*)(recs + (size_t)cur*8);
            k = ((unsigned long long)__float_as_uint(dn.x) << 32) |
                (unsigned int)cur;
            cur = __float_as_int(dn.y);
        }
        keys[i] = k;
    }
    bool overflow = (cur >= 0);

    float T = 1.0f, accA = 0.f, accD = 0.f, aR = 0.f, aG = 0.f, aB = 0.f;

    if (!overflow){
        for (int it = 0; it < KMAX; ++it){
            unsigned long long m0 = umin64(keys[0],  keys[1]);
            unsigned long long m1 = umin64(keys[2],  keys[3]);
            unsigned long long m2 = umin64(keys[4],  keys[5]);
            unsigned long long m3 = umin64(keys[6],  keys[7]);
            unsigned long long m4 = umin64(keys[8],  keys[9]);
            unsigned long long m5 = umin64(keys[10], keys[11]);
            unsigned long long m6 = umin64(keys[12], keys[13]);
            unsigned long long m7 = umin64(keys[14], keys[15]);
            m0 = umin64(m0, m1); m2 = umin64(m2, m3);
            m4 = umin64(m4, m5); m6 = umin64(m6, m7);
            m0 = umin64(m0, m2); m4 = umin64(m4, m6);
            unsigned long long m = umin64(m0, m4);

            if (!__any(m != NONE)) break;

            if (m != NONE){
                int nidx = (int)(m & 0xffffffffu);
                float4 ra = *(const float4*)(recs + (size_t)nidx*8);
                float2 rb = *(const float2*)(recs + (size_t)nidx*8 + 4);
                float a = ra.z, w = a*T;
                aR += w*ra.w; aG += w*rb.x; aB += w*rb.y;
                accA += w; accD += w*ra.x;
                T *= (1.0f - a);
                #pragma unroll
                for (int j = 0; j < KMAX; j++)
                    keys[j] = (keys[j] == m) ? NONE : keys[j];
            }
        }
    } else {
        unsigned long long last = 0; bool haveLast = false;
        for (;;){
            unsigned long long best = NONE;
            for (int c2 = heads[p]; c2 >= 0; ){
                float2 dn = *(const float2*)(recs + (size_t)c2*8);
                unsigned long long k =
                    ((unsigned long long)__float_as_uint(dn.x) << 32) |
                    (unsigned int)c2;
                if ((!haveLast || k > last) && k < best) best = k;
                c2 = __float_as_int(dn.y);
            }
            if (best == NONE) break;
            int nidx = (int)(best & 0xffffffffu);
            float4 ra = *(const float4*)(recs + (size_t)nidx*8);
            float2 rb = *(const float2*)(recs + (size_t)nidx*8 + 4);
            float a = ra.z, w = a*T;
            aR += w*ra.w; aG += w*rb.x; aB += w*rb.y;
            accA += w; accD += w*ra.x;
            T *= (1.0f - a);
            last = best; haveLast = true;
        }
    }

    float om = 1.0f - accA;
    out[p]         = aR + om*bg[0];
    out[HWW + p]   = aG + om*bg[1];
    out[2*HWW + p] = aB + om*bg[2];
    out[3*HWW + p] = accD;
    out[4*HWW + p] = accA;
    out[5*HWW + p] = accD/(accA + 1e-8f);
}

extern "C" void kernel_launch(void* const* d_in, const int* in_sizes, int n_in,
                              void* d_out, int out_size, void* d_ws, size_t ws_size,
                              hipStream_t stream)
{
    const float* positions = (const float*)d_in[0];
    const float* trivecs   = (const float*)d_in[1];
    const float* densities = (const float*)d_in[2];
    const float* shs       = (const float*)d_in[3];
    const float* viewm     = (const float*)d_in[4];
    const float* projm     = (const float*)d_in[5];
    const float* campos    = (const float*)d_in[6];
    const float* aabb      = (const float*)d_in[7];
    const float* bg        = (const float*)d_in[8];
    float* out = (float*)d_out;

    char* ws = (char*)d_ws;
    size_t o = 0;
    int*   heads = (int*)(ws + o);   o += (size_t)HWW*4;
    float* recs  = (float*)(ws + o); o += (size_t)NP*32;

    hipMemsetAsync(heads, 0xFF, (size_t)HWW*4, stream);   // all -1
    point_kernel<<<NP/PPB, 256, 0, stream>>>(positions, trivecs, densities, shs,
                                             viewm, projm, campos, aabb,
                                             recs, heads);
    composite_kernel<<<HWW/256, 256, 0, stream>>>(heads, recs, bg, out);
}